// Round 1
// baseline (577.686 us; speedup 1.0000x reference)
//
#include <hip/hip_runtime.h>
#include <cmath>

// Problem constants (match reference)
#define NPROP 1500
#define NA 64        // actions
#define NC 81        // detection classes
#define PERSON_IDX 2

// ws layout (floats): [0]=humaness [1]=objectness [2]=cx [3]=cy
//                     [4]=1/w [5]=1/h [6]=log w [7]=log h   (each NPROP long)

__global__ void prep_kernel(const float* __restrict__ scores,
                            const float* __restrict__ bbox,
                            float* __restrict__ ws) {
    int i = blockIdx.x * blockDim.x + threadIdx.x;
    if (i >= NPROP) return;
    const float* s = scores + (size_t)i * NC;
    float best = s[0];
    int bidx = 0;
    #pragma unroll 4
    for (int c = 1; c < NC; ++c) {
        float v = s[c];
        if (v > best) { best = v; bidx = c; }   // strict > keeps first max (np.argmax)
    }
    float hum = (bidx == PERSON_IDX) ? best : 0.0f;
    float obj = (bidx == PERSON_IDX) ? 0.0f : best;

    float x0 = bbox[i*4+0], y0 = bbox[i*4+1], x1 = bbox[i*4+2], y1 = bbox[i*4+3];
    float w = x1 - x0, h = y1 - y0;
    float cx = x0 + 0.5f * w, cy = y0 + 0.5f * h;

    ws[0*NPROP + i] = hum;
    ws[1*NPROP + i] = obj;
    ws[2*NPROP + i] = cx;
    ws[3*NPROP + i] = cy;
    ws[4*NPROP + i] = 1.0f / w;
    ws[5*NPROP + i] = 1.0f / h;
    ws[6*NPROP + i] = logf(w);
    ws[7*NPROP + i] = logf(h);
}

// block = 256 threads: q = tid&15 -> action group (4 actions), r = tid>>4 -> o-in-tile
// grid  = (NPROP, GY); block loops over o-tiles of 16 with stride GY.
__global__ __launch_bounds__(256) void score_kernel(
        const float* __restrict__ logits,   // [N, 64]
        const float* __restrict__ mu,       // [N, 64, 4]
        const float* __restrict__ ws,
        float4* __restrict__ out4) {        // [N, N, 16] float4
    const int h = blockIdx.x;
    const int q = threadIdx.x & 15;
    const int r = threadIdx.x >> 4;
    const int NT = (NPROP + 15) / 16;       // 94 tiles

    const float hum = ws[0*NPROP + h];      // wave-uniform branch below

    if (hum == 0.0f) {
        // entire h-row is exactly zero in the reference -> streamed zero-fill
        const float4 z = make_float4(0.f, 0.f, 0.f, 0.f);
        for (int t = blockIdx.y; t < NT; t += gridDim.y) {
            int o = t * 16 + r;
            if (o < NPROP) {
                out4[((size_t)h * NPROP + o) * 16 + q] = z;
            }
        }
        return;
    }

    // --- person row: real compute (~18 rows total) ---
    const float cxh = ws[2*NPROP + h], cyh = ws[3*NPROP + h];
    const float iwh = ws[4*NPROP + h], ihh = ws[5*NPROP + h];
    const float lwh = ws[6*NPROP + h], lhh = ws[7*NPROP + h];

    // per-thread action data: actions 4q..4q+3 of row h, register-resident
    const float4* muv = (const float4*)(mu + ((size_t)h * NA + 4 * q) * 4);
    const float4 m0 = muv[0], m1 = muv[1], m2 = muv[2], m3 = muv[3];
    const float4 lg = ((const float4*)(logits + (size_t)h * NA))[q];
    const float sa0 = hum * lg.x, sa1 = hum * lg.y, sa2 = hum * lg.z, sa3 = hum * lg.w;
    const float mm0 = m0.x*m0.x + m0.y*m0.y + m0.z*m0.z + m0.w*m0.w;
    const float mm1 = m1.x*m1.x + m1.y*m1.y + m1.z*m1.z + m1.w*m1.w;
    const float mm2 = m2.x*m2.x + m2.y*m2.y + m2.z*m2.z + m2.w*m2.w;
    const float mm3 = m3.x*m3.x + m3.y*m3.y + m3.z*m3.z + m3.w*m3.w;

    // compat = exp(-d * inv2s2) = exp2(C * d),  C = -inv2s2 * log2(e)
    const float INV2S2 = 1.0f / (2.0f * 0.3f * 0.3f);
    const float C = -INV2S2 * 1.4426950408889634f;

    for (int t = blockIdx.y; t < NT; t += gridDim.y) {
        int o = t * 16 + r;
        if (o >= NPROP) continue;
        const float obj = ws[1*NPROP + o];
        const float tx = (ws[2*NPROP + o] - cxh) * iwh;
        const float ty = (ws[3*NPROP + o] - cyh) * ihh;
        const float tw = ws[6*NPROP + o] - lwh;
        const float th = ws[7*NPROP + o] - lhh;
        const float e2 = tx*tx + ty*ty + tw*tw + th*th;

        const float d0 = e2 + mm0 - 2.0f * (tx*m0.x + ty*m0.y + tw*m0.z + th*m0.w);
        const float d1 = e2 + mm1 - 2.0f * (tx*m1.x + ty*m1.y + tw*m1.z + th*m1.w);
        const float d2 = e2 + mm2 - 2.0f * (tx*m2.x + ty*m2.y + tw*m2.z + th*m2.w);
        const float d3 = e2 + mm3 - 2.0f * (tx*m3.x + ty*m3.y + tw*m3.z + th*m3.w);

        float4 res;
        res.x = sa0 * obj * exp2f(C * d0);
        res.y = sa1 * obj * exp2f(C * d1);
        res.z = sa2 * obj * exp2f(C * d2);
        res.w = sa3 * obj * exp2f(C * d3);

        out4[((size_t)h * NPROP + o) * 16 + q] = res;
    }
}

extern "C" void kernel_launch(void* const* d_in, const int* in_sizes, int n_in,
                              void* d_out, int out_size, void* d_ws, size_t ws_size,
                              hipStream_t stream) {
    const float* action_logits = (const float*)d_in[0];  // [N, 64]
    const float* target_mean   = (const float*)d_in[1];  // [N, 64, 4]
    const float* bbox          = (const float*)d_in[2];  // [N, 4]
    const float* scores        = (const float*)d_in[3];  // [N, 81]
    float* out = (float*)d_out;                          // [N, N, 64]
    float* ws  = (float*)d_ws;                           // needs 8*N floats = 48 KB

    prep_kernel<<<(NPROP + 255) / 256, 256, 0, stream>>>(scores, bbox, ws);

    const int GY = 8;
    dim3 grid(NPROP, GY);
    score_kernel<<<grid, 256, 0, stream>>>(action_logits, target_mean, ws,
                                           (float4*)out);
}

// Round 2
// 568.926 us; speedup vs baseline: 1.0154x; 1.0154x over previous
//
#include <hip/hip_runtime.h>
#include <cmath>

// Problem constants (match reference)
#define NPROP 1500
#define NA 64        // actions
#define NC 81        // detection classes
#define PERSON_IDX 2

// ws layout (floats): [0]=humaness [1]=objectness [2]=cx [3]=cy
//                     [4]=1/w [5]=1/h [6]=log w [7]=log h   (each NPROP long)

__global__ void prep_kernel(const float* __restrict__ scores,
                            const float* __restrict__ bbox,
                            float* __restrict__ ws) {
    int i = blockIdx.x * blockDim.x + threadIdx.x;
    if (i >= NPROP) return;
    const float* s = scores + (size_t)i * NC;
    float best = s[0];
    int bidx = 0;
    #pragma unroll 4
    for (int c = 1; c < NC; ++c) {
        float v = s[c];
        if (v > best) { best = v; bidx = c; }   // strict > keeps first max (np.argmax)
    }
    float hum = (bidx == PERSON_IDX) ? best : 0.0f;
    float obj = (bidx == PERSON_IDX) ? 0.0f : best;

    float x0 = bbox[i*4+0], y0 = bbox[i*4+1], x1 = bbox[i*4+2], y1 = bbox[i*4+3];
    float w = x1 - x0, h = y1 - y0;
    float cx = x0 + 0.5f * w, cy = y0 + 0.5f * h;

    ws[0*NPROP + i] = hum;
    ws[1*NPROP + i] = obj;
    ws[2*NPROP + i] = cx;
    ws[3*NPROP + i] = cy;
    ws[4*NPROP + i] = 1.0f / w;
    ws[5*NPROP + i] = 1.0f / h;
    ws[6*NPROP + i] = logf(w);
    ws[7*NPROP + i] = logf(h);
}

// Runs AFTER hipMemsetAsync(out, 0). Only person rows (~18 of 1500) do work;
// all other blocks exit after one scalar load. block=256: q=tid&15 -> action
// group of 4, r=tid>>4 -> o within a 16-wide tile; grid=(NPROP, GY).
__global__ __launch_bounds__(256) void person_rows_kernel(
        const float* __restrict__ logits,   // [N, 64]
        const float* __restrict__ mu,       // [N, 64, 4]
        const float* __restrict__ ws,
        float4* __restrict__ out4) {        // [N, N, 16] float4
    const int h = blockIdx.x;
    const float hum = ws[0*NPROP + h];      // wave-uniform
    if (hum == 0.0f) return;                // zero row: memset already wrote it

    const int q = threadIdx.x & 15;
    const int r = threadIdx.x >> 4;
    const int NT = (NPROP + 15) / 16;       // 94 tiles

    const float cxh = ws[2*NPROP + h], cyh = ws[3*NPROP + h];
    const float iwh = ws[4*NPROP + h], ihh = ws[5*NPROP + h];
    const float lwh = ws[6*NPROP + h], lhh = ws[7*NPROP + h];

    // actions 4q..4q+3 of row h, register-resident across the o-loop
    const float4* muv = (const float4*)(mu + ((size_t)h * NA + 4 * q) * 4);
    const float4 m0 = muv[0], m1 = muv[1], m2 = muv[2], m3 = muv[3];
    const float4 lg = ((const float4*)(logits + (size_t)h * NA))[q];
    const float sa0 = hum * lg.x, sa1 = hum * lg.y, sa2 = hum * lg.z, sa3 = hum * lg.w;
    const float mm0 = m0.x*m0.x + m0.y*m0.y + m0.z*m0.z + m0.w*m0.w;
    const float mm1 = m1.x*m1.x + m1.y*m1.y + m1.z*m1.z + m1.w*m1.w;
    const float mm2 = m2.x*m2.x + m2.y*m2.y + m2.z*m2.z + m2.w*m2.w;
    const float mm3 = m3.x*m3.x + m3.y*m3.y + m3.z*m3.z + m3.w*m3.w;

    // compat = exp(-d * inv2s2) = exp2(C * d),  C = -inv2s2 * log2(e)
    const float INV2S2 = 1.0f / (2.0f * 0.3f * 0.3f);
    const float C = -INV2S2 * 1.4426950408889634f;

    for (int t = blockIdx.y; t < NT; t += gridDim.y) {
        int o = t * 16 + r;
        if (o >= NPROP) continue;
        const float obj = ws[1*NPROP + o];
        const float tx = (ws[2*NPROP + o] - cxh) * iwh;
        const float ty = (ws[3*NPROP + o] - cyh) * ihh;
        const float tw = ws[6*NPROP + o] - lwh;
        const float th = ws[7*NPROP + o] - lhh;
        const float e2 = tx*tx + ty*ty + tw*tw + th*th;

        const float d0 = e2 + mm0 - 2.0f * (tx*m0.x + ty*m0.y + tw*m0.z + th*m0.w);
        const float d1 = e2 + mm1 - 2.0f * (tx*m1.x + ty*m1.y + tw*m1.z + th*m1.w);
        const float d2 = e2 + mm2 - 2.0f * (tx*m2.x + ty*m2.y + tw*m2.z + th*m2.w);
        const float d3 = e2 + mm3 - 2.0f * (tx*m3.x + ty*m3.y + tw*m3.z + th*m3.w);

        float4 res;
        res.x = sa0 * obj * exp2f(C * d0);
        res.y = sa1 * obj * exp2f(C * d1);
        res.z = sa2 * obj * exp2f(C * d2);
        res.w = sa3 * obj * exp2f(C * d3);

        out4[((size_t)h * NPROP + o) * 16 + q] = res;
    }
}

extern "C" void kernel_launch(void* const* d_in, const int* in_sizes, int n_in,
                              void* d_out, int out_size, void* d_ws, size_t ws_size,
                              hipStream_t stream) {
    const float* action_logits = (const float*)d_in[0];  // [N, 64]
    const float* target_mean   = (const float*)d_in[1];  // [N, 64, 4]
    const float* bbox          = (const float*)d_in[2];  // [N, 4]
    const float* scores        = (const float*)d_in[3];  // [N, 81]
    float* out = (float*)d_out;                          // [N, N, 64]
    float* ws  = (float*)d_ws;                           // needs 8*N floats = 48 KB

    // Bulk zero of the whole output via the rocclr fill path (6.2 TB/s measured
    // on this very buffer). Person rows (~1.2%) are overwritten afterwards.
    hipMemsetAsync(out, 0, (size_t)out_size * sizeof(float), stream);

    prep_kernel<<<(NPROP + 255) / 256, 256, 0, stream>>>(scores, bbox, ws);

    const int GY = 8;
    dim3 grid(NPROP, GY);
    person_rows_kernel<<<grid, 256, 0, stream>>>(action_logits, target_mean, ws,
                                                 (float4*)out);
}